// Round 2
// baseline (668.270 us; speedup 1.0000x reference)
//
#include <hip/hip_runtime.h>

typedef _Float16 half8  __attribute__((ext_vector_type(8)));
typedef float    floatx4 __attribute__((ext_vector_type(4)));

#define HW      128
#define CIN     256
#define NCHUNK  8
#define HALO_W  24      // 16 + 2*4
#define HALO_H  16      // 8 + 2*4
#define PITCH   20      // u32 per pixel row: 32 halfs data + 8 halfs pad = 40 halfs

// Binarize weights -> f16 (+1/-1), layout Wp[b][t][co][ci] (ci contiguous).
__global__ void prep_weights(const float* __restrict__ w1,
                             const float* __restrict__ w2,
                             const float* __restrict__ w3,
                             const float* __restrict__ w4,
                             _Float16* __restrict__ wp)
{
    int idx  = blockIdx.x * 256 + threadIdx.x;   // 0 .. 327679 = 4*5*64*256
    int ci   = idx & 255;
    int rest = idx >> 8;
    int co   = rest & 63;
    int bt   = rest >> 6;                        // 0..19
    int t    = bt % 5;
    int b    = bt / 5;
    const float* w = (b == 0) ? w1 : (b == 1) ? w2 : (b == 2) ? w3 : w4;
    float v = w[(co * 256 + ci) * 5 + t];
    wp[idx] = (v < 0.0f) ? (_Float16)(-1.0f) : (_Float16)(1.0f);
}

// One WG per (16w x 8h) tile per image. 4 waves = 4 branches.
// Wave computes 64 co x 128 pix via mfma_f32_16x16x32_f16.
__global__ __launch_bounds__(256, 2)
void bconv_mfma(const float* __restrict__ x,
                const _Float16* __restrict__ wp,
                const float* __restrict__ bb1,
                const float* __restrict__ bb2,
                const float* __restrict__ bb3,
                const float* __restrict__ bb4,
                float* __restrict__ out)
{
    __shared__ __align__(16) unsigned int xs[HALO_H * HALO_W * PITCH]; // 30720 B
    __shared__ float bias_s[256];

    const int tid  = threadIdx.x;
    const int w0t  = blockIdx.x * 16;
    const int h0t  = blockIdx.y * 8;
    const int nimg = blockIdx.z;

    {   // stage all 256 biases (branch-major) into LDS
        int br = tid >> 6, i = tid & 63;
        const float* bp = (br == 0) ? bb1 : (br == 1) ? bb2 : (br == 2) ? bb3 : bb4;
        bias_s[tid] = bp[i];
    }

    const int lane = tid & 63;
    const int wave = tid >> 6;          // branch id: 0=H d1, 1=H d2, 2=V d1, 3=V d2
    const int quad = lane >> 4;
    const int wl   = lane & 15;

    floatx4 acc[4][8];
    #pragma unroll
    for (int m = 0; m < 4; ++m)
        #pragma unroll
        for (int n = 0; n < 8; ++n)
            acc[m][n] = (floatx4){0.f, 0.f, 0.f, 0.f};

    const int  dil   = (wave & 1) + 1;
    const bool horiz = (wave < 2);

    for (int chunk = 0; chunk < NCHUNK; ++chunk) {
        __syncthreads();   // previous chunk's reads done (also covers bias_s)

        // ---- stage 24x16 halo x 32 ci, fp32 -> f16, zero-pad out of image ----
        #pragma unroll
        for (int s = 0; s < 6; ++s) {
            int u   = s * 256 + tid;        // 0..1535
            int f   = u % 6;                // float4 column block in halo row
            int g   = u / 6;                // 0..255
            int hh  = g & 15;               // halo row
            int cp  = g >> 4;               // ci pair 0..15
            int ci0 = chunk * 32 + cp * 2;
            int hg  = h0t - 4 + hh;
            int wg  = w0t - 4 + f * 4;      // multiple of 4 -> float4 aligned
            floatx4 v0 = {0.f,0.f,0.f,0.f}, v1 = {0.f,0.f,0.f,0.f};
            if (hg >= 0 && hg < HW && wg >= 0 && wg <= HW - 4) {
                const floatx4* p = (const floatx4*)(x + ((nimg * CIN + ci0) * HW + hg) * HW + wg);
                v0 = p[0];
                v1 = p[(HW * HW) / 4];      // ci0 + 1
            }
            int pixb = hh * HALO_W + f * 4;
            #pragma unroll
            for (int i = 0; i < 4; ++i) {
                xs[(pixb + i) * PITCH + cp] =
                    __builtin_bit_cast(unsigned int,
                        __builtin_amdgcn_cvt_pkrtz(v0[i], v1[i]));
            }
        }
        __syncthreads();

        // ---- compute: 5 taps x 4 co-tiles x 8 rows ----
        #pragma unroll
        for (int t = 0; t < 5; ++t) {
            half8 B[8];
            #pragma unroll
            for (int n = 0; n < 8; ++n) {
                int hh, ww;
                if (horiz) { hh = n + 4;                  ww = wl + 4 + (t - 2) * dil; }
                else       { hh = n + 4 + (t - 2) * dil;  ww = wl + 4; }
                B[n] = *(const half8*)&xs[(hh * HALO_W + ww) * PITCH + quad * 4];
            }
            #pragma unroll
            for (int m = 0; m < 4; ++m) {
                half8 A = *(const half8*)(wp +
                    (((wave * 5 + t) * 64 + m * 16 + wl) * 256 + chunk * 32 + quad * 8));
                #pragma unroll
                for (int n = 0; n < 8; ++n)
                    acc[m][n] = __builtin_amdgcn_mfma_f32_16x16x32_f16(A, B[n], acc[m][n], 0, 0, 0);
            }
        }
    }

    // ---- epilogue: bias + store (D: col=lane&15 -> w, row=quad*4+r -> co) ----
    float bv[4][4];
    #pragma unroll
    for (int m = 0; m < 4; ++m)
        #pragma unroll
        for (int r = 0; r < 4; ++r)
            bv[m][r] = bias_s[wave * 64 + m * 16 + quad * 4 + r];

    #pragma unroll
    for (int m = 0; m < 4; ++m) {
        #pragma unroll
        for (int n = 0; n < 8; ++n) {
            int co   = wave * 64 + m * 16 + quad * 4;
            int base = ((nimg * 256 + co) * HW + (h0t + n)) * HW + w0t + wl;
            #pragma unroll
            for (int r = 0; r < 4; ++r)
                out[base + r * HW * HW] = acc[m][n][r] + bv[m][r];
        }
    }
}

extern "C" void kernel_launch(void* const* d_in, const int* in_sizes, int n_in,
                              void* d_out, int out_size, void* d_ws, size_t ws_size,
                              hipStream_t stream)
{
    (void)in_sizes; (void)n_in; (void)out_size; (void)ws_size;
    const float* x  = (const float*)d_in[0];
    const float* w1 = (const float*)d_in[1];
    const float* b1 = (const float*)d_in[2];
    const float* w2 = (const float*)d_in[3];
    const float* b2 = (const float*)d_in[4];
    const float* w3 = (const float*)d_in[5];
    const float* b3 = (const float*)d_in[6];
    const float* w4 = (const float*)d_in[7];
    const float* b4 = (const float*)d_in[8];
    float*    out = (float*)d_out;
    _Float16* wp  = (_Float16*)d_ws;   // 655360 B

    prep_weights<<<1280, 256, 0, stream>>>(w1, w2, w3, w4, wp);

    dim3 grid(128 / 16, 128 / 8, 16);
    bconv_mfma<<<grid, dim3(256), 0, stream>>>(x, wp, b1, b2, b3, b4, out);
}